// Round 4
// baseline (134.659 us; speedup 1.0000x reference)
//
#include <hip/hip_runtime.h>

// LIF neuron bank: B=16, N=2048, T=1000. Sequential scan in T per neuron.
//
// R3: R2's producer/consumer structure, but with RAW barriers.
// __syncthreads() lowers to "s_waitcnt vmcnt(0) expcnt(0) lgkmcnt(0); s_barrier",
// which forced every storer wave to drain its global stores to COMPLETION at
// each of the 25 chunk barriers (store latency x 25 on the critical path),
// and drained the compute wave's prefetch loads. We only need LDS ordering:
//   asm(s_waitcnt lgkmcnt(0)) + __builtin_amdgcn_s_barrier().
// Global stores stay in flight across barriers (vmcnt is per-wave); HBM
// back-pressure paces the pipeline at bandwidth rate, not latency rate.
//
// Layout per block (512 blocks x 192 threads):
//   wave 0: compute 64 neurons, double-buffered register u-loads, writes
//           s/v to LDS [par][t][lane] (lane=neuron -> conflict-free b32).
//   wave 1: spikes LDS->global, float4 back-to-back.
//   wave 2: vhist  LDS->global.
// Double-buffered LDS: compute writes par=c&1, storers read (c-1)&1.
//
// FP discipline: reference does NOT contract mul+add into FMA; use
// __fmul_rn/__fadd_rn/__fsub_rn to stay bit-exact (R0-R2: absmax 0.0).

constexpr int B_ = 16;
constexpr int N_ = 2048;
constexpr int T_ = 1000;
constexpr int CHUNK = 40;            // steps per chunk
constexpr int NV4 = CHUNK / 4;       // 10 float4 per chunk
constexpr int NCHUNK = T_ / CHUNK;   // 25 chunks
constexpr int NPAIR = NCHUNK / 2;    // 12 pairs + 1 tail chunk

// LDS-only barrier: order ds ops, do NOT drain global stores/loads.
#define LDS_BARRIER()                                          \
    do {                                                       \
        asm volatile("s_waitcnt lgkmcnt(0)" ::: "memory");     \
        __builtin_amdgcn_s_barrier();                          \
    } while (0)

__global__ __launch_bounds__(192) void lif_kernel(
    const float* __restrict__ u,          // (B, N, T)
    const float* __restrict__ theta_base, // (1, N, 1) -> N floats
    float* __restrict__ spikes,           // (B, N, T)
    float* __restrict__ vhist)            // (B, N, T)
{
    __shared__ float s_lds[2][CHUNK][64];   // [par][t][neuron]
    __shared__ float v_lds[2][CHUNK][64];

    const int lane = threadIdx.x & 63;
    const int wid = threadIdx.x >> 6;
    const int neuron = blockIdx.x * 64 + lane;   // 512*64 = 32768 = B*N
    const size_t row = (size_t)neuron * T_;

    if (wid == 0) {
        // ---------------- compute wave ----------------
        const float tb = theta_base[neuron & (N_ - 1)];
        const float c5 = __fmul_rn(tb, 0.005f);   // tb * (1-0.995) rounded
        float v = 0.0f, theta = tb, ref = 0.0f;
        const float* up = u + row;

        float4 bufA[NV4], bufB[NV4];   // named bufs: static indexing only

        auto load_chunk = [&](float4 (&buf)[NV4], int t0) {
#pragma unroll
            for (int i = 0; i < NV4; ++i)
                buf[i] = *reinterpret_cast<const float4*>(up + t0 + 4 * i);
        };

        auto process = [&](const float4 (&buf)[NV4], int par) {
#pragma unroll
            for (int i = 0; i < NV4; ++i) {
                const float uin[4] = {buf[i].x, buf[i].y, buf[i].z, buf[i].w};
#pragma unroll
                for (int k = 0; k < 4; ++k) {
                    // u_eff = u_t * (1 - (ref>0))
                    const float ueff = (ref > 0.0f) ? 0.0f : uin[k];
                    // v = 0.95*v + u_eff   (separate mul/add, no FMA)
                    v = __fadd_rn(__fmul_rn(0.95f, v), ueff);
                    // s = (v - theta >= 0)
                    const float d = __fsub_rn(v, theta);
                    const bool s = (d >= 0.0f);
                    // v -= s*theta
                    v = s ? __fsub_rn(v, theta) : v;
                    // ref = max(ref-1,0); if (s) ref = 2
                    ref = fmaxf(__fsub_rn(ref, 1.0f), 0.0f);
                    ref = s ? 2.0f : ref;
                    // theta = theta*0.995 + tb*0.005 + 0.35*s
                    theta = __fadd_rn(__fmul_rn(theta, 0.995f), c5);
                    theta = s ? __fadd_rn(theta, 0.35f) : theta;

                    s_lds[par][4 * i + k][lane] = s ? 1.0f : 0.0f;
                    v_lds[par][4 * i + k][lane] = v;
                }
            }
        };

        load_chunk(bufA, 0);
        int t = 0;
#pragma unroll 1
        for (int c = 0; c < NPAIR; ++c) {
            load_chunk(bufB, t + CHUNK);   // chunk 2c+1
            process(bufA, 0);              // chunk 2c   -> par 0
            LDS_BARRIER();
            t += CHUNK;
            load_chunk(bufA, t + CHUNK);   // chunk 2c+2 (<=24, always valid)
            process(bufB, 1);              // chunk 2c+1 -> par 1
            LDS_BARRIER();
            t += CHUNK;
        }
        process(bufA, 0);                  // chunk 24 -> par 0
        LDS_BARRIER();                     // barrier #25
    } else {
        // ---------------- storer waves ----------------
        float* gout = (wid == 1) ? spikes : vhist;
        const float (*src)[CHUNK][64] = (wid == 1) ? s_lds : v_lds;
        float* gp = gout + row;

#pragma unroll 1
        for (int c = 0; c < NCHUNK; ++c) {
            if (c > 0) {
                const int par = (c - 1) & 1;
                const int t0 = (c - 1) * CHUNK;
#pragma unroll
                for (int i = 0; i < NV4; ++i) {
                    float4 w;
                    w.x = src[par][4 * i + 0][lane];
                    w.y = src[par][4 * i + 1][lane];
                    w.z = src[par][4 * i + 2][lane];
                    w.w = src[par][4 * i + 3][lane];
                    *reinterpret_cast<float4*>(gp + t0 + 4 * i) = w;
                }
            }
            LDS_BARRIER();
        }
        // tail: chunk 24 lives in par 0; compute's barrier #25 already passed
        {
            const int t0 = (NCHUNK - 1) * CHUNK;
#pragma unroll
            for (int i = 0; i < NV4; ++i) {
                float4 w;
                w.x = src[0][4 * i + 0][lane];
                w.y = src[0][4 * i + 1][lane];
                w.z = src[0][4 * i + 2][lane];
                w.w = src[0][4 * i + 3][lane];
                *reinterpret_cast<float4*>(gp + t0 + 4 * i) = w;
            }
        }
    }
}

extern "C" void kernel_launch(void* const* d_in, const int* in_sizes, int n_in,
                              void* d_out, int out_size, void* d_ws, size_t ws_size,
                              hipStream_t stream) {
    const float* u = (const float*)d_in[0];           // (B,N,T)
    const float* theta_base = (const float*)d_in[1];  // (1,N,1)
    float* out = (float*)d_out;
    float* spikes = out;                               // first output
    float* vhist = out + (size_t)B_ * N_ * T_;         // second output

    const int grid = (B_ * N_) / 64;   // 512 blocks (64 neurons each)
    lif_kernel<<<grid, 192, 0, stream>>>(u, theta_base, spikes, vhist);
}

// Round 5
// 109.827 us; speedup vs baseline: 1.2261x; 1.2261x over previous
//
#include <hip/hip_runtime.h>

// LIF neuron bank: B=16, N=2048, T=1000. Sequential scan in T per neuron.
//
// R4: fix store coalescing. R0-R3 stored 64 lanes x 16B at 4000B stride =
// 64 scattered 16B segments PER INSTRUCTION (and same for loads); the CU->L2
// path is transaction-limited on that pattern (fillBuffer hits 7 TB/s with
// contiguous stores on this chip; we sat at 2.5 TB/s). Now:
//   - compute wave packs 4 steps into float4 regs, one swizzled ds_write_b128
//     per output per 4 steps into LDS[par][row][tf] (tf = t/4 within chunk).
//   - storer waves read LDS (inverse swizzle) and write ROW-CONTIGUOUS
//     segments: inst k covers rows 4k..4k+3; 16 consecutive lanes write 16
//     consecutive float4 of one row = 4x 256B contiguous segments/inst.
//   - XOR swizzle phys_tf = tf ^ (row & 15): bijective per row, float4-
//     granular (16B alignment preserved), spreads bank groups on both the
//     write side (row=lane, tf fixed) and read side (tf=lane&15, row fixed).
// CHUNK=64 steps -> LDS 2 outputs x [2][64][16] float4 = 64KB -> 2 blocks/CU.
// Barriers are LDS-only (lgkmcnt + s_barrier); global stores never drained
// in-loop (vmcnt is per-wave, stores stay in flight across barriers).
// Tail (t=960..999, 40 steps) uses the old scattered path (4% of traffic).
//
// FP discipline: reference does NOT contract mul+add into FMA; use
// __fmul_rn/__fadd_rn/__fsub_rn to stay bit-exact (R0-R3: absmax 0.0).

constexpr int B_ = 16;
constexpr int N_ = 2048;
constexpr int T_ = 1000;
constexpr int CHUNK = 64;                 // steps per full chunk
constexpr int NF4 = CHUNK / 4;            // 16 float4 per row per chunk
constexpr int NFULL = 15;                 // full chunks (0..14)
constexpr int NPAIR = 7;                  // chunk pairs in pipeline
constexpr int TAIL_T0 = NFULL * CHUNK;    // 960
constexpr int TAIL_F4 = (T_ - TAIL_T0) / 4;  // 10 float4

// LDS-only barrier: order ds ops, do NOT drain global stores/loads.
#define LDS_BARRIER()                                          \
    do {                                                       \
        asm volatile("s_waitcnt lgkmcnt(0)" ::: "memory");     \
        __builtin_amdgcn_s_barrier();                          \
    } while (0)

__global__ __launch_bounds__(192) void lif_kernel(
    const float* __restrict__ u,          // (B, N, T)
    const float* __restrict__ theta_base, // (1, N, 1) -> N floats
    float* __restrict__ spikes,           // (B, N, T)
    float* __restrict__ vhist)            // (B, N, T)
{
    __shared__ float4 s_lds[2][64][NF4];   // [par][row][phys_tf]
    __shared__ float4 v_lds[2][64][NF4];

    const int lane = threadIdx.x & 63;
    const int wid = threadIdx.x >> 6;
    const int blk0 = blockIdx.x * 64;            // first neuron of block
    const size_t row = (size_t)(blk0 + lane) * T_;

    if (wid == 0) {
        // ---------------- compute wave ----------------
        const float tb = theta_base[(blk0 + lane) & (N_ - 1)];
        const float c5 = __fmul_rn(tb, 0.005f);   // tb * (1-0.995) rounded
        float v = 0.0f, theta = tb, ref = 0.0f;
        const float* up = u + row;

        float4 bufA[NF4], bufB[NF4];   // named bufs: static indexing only

        auto load_full = [&](float4 (&buf)[NF4], int t0) {
#pragma unroll
            for (int i = 0; i < NF4; ++i)
                buf[i] = *reinterpret_cast<const float4*>(up + t0 + 4 * i);
        };
        auto load_tail = [&](float4 (&buf)[NF4]) {
#pragma unroll
            for (int i = 0; i < TAIL_F4; ++i)
                buf[i] = *reinterpret_cast<const float4*>(up + TAIL_T0 + 4 * i);
        };

        // 4 LIF steps on one float4 of input; write s/v float4 to LDS.
        auto step4 = [&](const float4 u4, int par, int tf) {
            const float uin[4] = {u4.x, u4.y, u4.z, u4.w};
            float so[4], vo[4];
#pragma unroll
            for (int k = 0; k < 4; ++k) {
                // u_eff = u_t * (1 - (ref>0))
                const float ueff = (ref > 0.0f) ? 0.0f : uin[k];
                // v = 0.95*v + u_eff   (separate mul/add, no FMA)
                v = __fadd_rn(__fmul_rn(0.95f, v), ueff);
                // s = (v - theta >= 0)
                const float d = __fsub_rn(v, theta);
                const bool s = (d >= 0.0f);
                // v -= s*theta
                v = s ? __fsub_rn(v, theta) : v;
                // ref = max(ref-1,0); if (s) ref = 2
                ref = fmaxf(__fsub_rn(ref, 1.0f), 0.0f);
                ref = s ? 2.0f : ref;
                // theta = theta*0.995 + tb*0.005 + 0.35*s
                theta = __fadd_rn(__fmul_rn(theta, 0.995f), c5);
                theta = s ? __fadd_rn(theta, 0.35f) : theta;

                so[k] = s ? 1.0f : 0.0f;
                vo[k] = v;
            }
            const int ptf = tf ^ (lane & 15);     // swizzled float4 slot
            s_lds[par][lane][ptf] = make_float4(so[0], so[1], so[2], so[3]);
            v_lds[par][lane][ptf] = make_float4(vo[0], vo[1], vo[2], vo[3]);
        };

        auto process_full = [&](const float4 (&buf)[NF4], int par) {
#pragma unroll
            for (int tf = 0; tf < NF4; ++tf) step4(buf[tf], par, tf);
        };
        auto process_tail = [&](const float4 (&buf)[NF4], int par) {
#pragma unroll
            for (int tf = 0; tf < TAIL_F4; ++tf) step4(buf[tf], par, tf);
        };

        load_full(bufA, 0);
        int t = 0;
#pragma unroll 1
        for (int p = 0; p < NPAIR; ++p) {
            load_full(bufB, t + CHUNK);     // chunk 2p+1
            process_full(bufA, 0);          // chunk 2p   -> par 0
            LDS_BARRIER();
            t += CHUNK;
            load_full(bufA, t + CHUNK);     // chunk 2p+2 (<=14: in range)
            process_full(bufB, 1);          // chunk 2p+1 -> par 1
            LDS_BARRIER();
            t += CHUNK;
        }
        // t = 896: bufA holds chunk 14
        load_tail(bufB);                    // tail u (10 float4)
        process_full(bufA, 0);              // chunk 14 -> par 0
        LDS_BARRIER();                      // barrier #15
        process_tail(bufB, 1);              // tail -> par 1
        LDS_BARRIER();                      // barrier #16
    } else {
        // ---------------- storer waves ----------------
        float* gout = (wid == 1) ? spikes : vhist;
        const float4 (*src)[64][NF4] = (wid == 1) ? s_lds : v_lds;
        float* gp = gout + (size_t)blk0 * T_;

        const int tf = lane & 15;           // float4 index within row chunk
        const int rsub = lane >> 4;         // row within group of 4

#pragma unroll 1
        for (int c = 0; c < NFULL + 1; ++c) {   // phases 0..15
            if (c > 0) {
                const int par = (c - 1) & 1;
                const int t0 = (c - 1) * CHUNK;
#pragma unroll
                for (int k = 0; k < 16; ++k) {
                    const int r = 4 * k + rsub;
                    const float4 w = src[par][r][tf ^ (r & 15)];
                    *reinterpret_cast<float4*>(gp + (size_t)r * T_ + t0 + 4 * tf) = w;
                }
            }
            LDS_BARRIER();
        }
        // tail (chunk 15, par 1): scattered per-lane stores, 10 float4/row
        {
#pragma unroll
            for (int j = 0; j < TAIL_F4; ++j) {
                const float4 w = src[1][lane][j ^ (lane & 15)];
                *reinterpret_cast<float4*>(gp + (size_t)lane * T_ + TAIL_T0 + 4 * j) = w;
            }
        }
    }
}

extern "C" void kernel_launch(void* const* d_in, const int* in_sizes, int n_in,
                              void* d_out, int out_size, void* d_ws, size_t ws_size,
                              hipStream_t stream) {
    const float* u = (const float*)d_in[0];           // (B,N,T)
    const float* theta_base = (const float*)d_in[1];  // (1,N,1)
    float* out = (float*)d_out;
    float* spikes = out;                               // first output
    float* vhist = out + (size_t)B_ * N_ * T_;         // second output

    const int grid = (B_ * N_) / 64;   // 512 blocks (64 neurons each)
    lif_kernel<<<grid, 192, 0, stream>>>(u, theta_base, spikes, vhist);
}